// Round 4
// baseline (49.298 us; speedup 1.0000x reference)
//
#include <hip/hip_runtime.h>

// LIFSpike forward, T=4, tau=2, vth=1, vreset=0, decay_input=False, hard reset.
// x: (128,256,32,32) f32, viewed as (T=4, N=8388608) contiguous.
// per element i: v=0; for t: h = v*0.5 + x[t*N+i]; s = (h>=1); out = s; v = s?0:h.
//
// Cache-policy strategy (round 4): working set = 128 MiB in + 128 MiB out =
// 256 MiB = exactly L3 size -> thrashing (measured: only half the input stays
// resident, all writes reach HBM). Flip it: NT (no-allocate) LOADS stream the
// input from HBM without polluting L3; regular stores let the 128 MiB output
// live in the 256 MiB memory-side L3, where lines are re-dirtied in place
// every graph replay and need no HBM writeback. Steady-state HBM traffic
// ~= 128 MiB reads only.

typedef float f32x4 __attribute__((ext_vector_type(4)));

__global__ __launch_bounds__(256) void lif_spike_kernel(
    const f32x4* __restrict__ x, f32x4* __restrict__ out, int n4) {
    int i = blockIdx.x * blockDim.x + threadIdx.x;
    if (i >= n4) return;

    // Issue all 4 loads up front (independent addresses), NT policy.
    f32x4 x0 = __builtin_nontemporal_load(&x[(size_t)0 * n4 + i]);
    f32x4 x1 = __builtin_nontemporal_load(&x[(size_t)1 * n4 + i]);
    f32x4 x2 = __builtin_nontemporal_load(&x[(size_t)2 * n4 + i]);
    f32x4 x3 = __builtin_nontemporal_load(&x[(size_t)3 * n4 + i]);

    f32x4 v = (f32x4)(0.0f);
    f32x4 xs[4] = {x0, x1, x2, x3};
    #pragma unroll
    for (int t = 0; t < 4; ++t) {
        f32x4 h = v * 0.5f + xs[t];
        f32x4 s;
        s.x = (h.x >= 1.0f) ? 1.0f : 0.0f;
        s.y = (h.y >= 1.0f) ? 1.0f : 0.0f;
        s.z = (h.z >= 1.0f) ? 1.0f : 0.0f;
        s.w = (h.w >= 1.0f) ? 1.0f : 0.0f;
        out[(size_t)t * n4 + i] = s;  // regular store: allocate in L3, stay resident
        // hard reset: v_next = (h>=1) ? 0 : h
        v.x = (h.x >= 1.0f) ? 0.0f : h.x;
        v.y = (h.y >= 1.0f) ? 0.0f : h.y;
        v.z = (h.z >= 1.0f) ? 0.0f : h.z;
        v.w = (h.w >= 1.0f) ? 0.0f : h.w;
    }
}

extern "C" void kernel_launch(void* const* d_in, const int* in_sizes, int n_in,
                              void* d_out, int out_size, void* d_ws, size_t ws_size,
                              hipStream_t stream) {
    const float* x = (const float*)d_in[0];
    float* out = (float*)d_out;

    const int total = in_sizes[0];        // 33,554,432
    const int N = total / 4;              // per-timestep elements: 8,388,608
    const int n4 = N / 4;                 // float4 slots per timestep: 2,097,152

    const int block = 256;
    const int grid = (n4 + block - 1) / block;  // 8192 exact

    lif_spike_kernel<<<grid, block, 0, stream>>>(
        (const f32x4*)x, (f32x4*)out, n4);
}

// Round 5
// 43.041 us; speedup vs baseline: 1.1454x; 1.1454x over previous
//
#include <hip/hip_runtime.h>

// LIFSpike forward, T=4, tau=2, vth=1, vreset=0, decay_input=False, hard reset.
// x: (128,256,32,32) f32, viewed as (T=4, N=8388608) contiguous.
// per element i: v=0; for t: h = v*0.5 + x[t*N+i]; s = (h>=1); out = s; v = s?0:h.
//
// Round 5: cache policy reverted to round-3 best (cached loads so L3 keeps
// ~half the input resident; NT stores so the never-re-read output doesn't
// fight it). New lever: hoist all 4 loads up front as independent cached
// global_load_dwordx4 so each thread has 4 HBM transactions in flight
// (round 3's 16-VGPR version serialized them -> latency-bound at 4.5 TB/s).

typedef float f32x4 __attribute__((ext_vector_type(4)));

__global__ __launch_bounds__(256) void lif_spike_kernel(
    const f32x4* __restrict__ x, f32x4* __restrict__ out, int n4) {
    int i = blockIdx.x * blockDim.x + threadIdx.x;
    if (i >= n4) return;

    // 4 independent cached loads in flight.
    f32x4 x0 = x[(size_t)0 * n4 + i];
    f32x4 x1 = x[(size_t)1 * n4 + i];
    f32x4 x2 = x[(size_t)2 * n4 + i];
    f32x4 x3 = x[(size_t)3 * n4 + i];

    f32x4 v = (f32x4)(0.0f);
    f32x4 xs[4] = {x0, x1, x2, x3};
    #pragma unroll
    for (int t = 0; t < 4; ++t) {
        f32x4 h = v * 0.5f + xs[t];
        f32x4 s;
        s.x = (h.x >= 1.0f) ? 1.0f : 0.0f;
        s.y = (h.y >= 1.0f) ? 1.0f : 0.0f;
        s.z = (h.z >= 1.0f) ? 1.0f : 0.0f;
        s.w = (h.w >= 1.0f) ? 1.0f : 0.0f;
        __builtin_nontemporal_store(s, &out[(size_t)t * n4 + i]);
        // hard reset: v_next = (h>=1) ? 0 : h
        v.x = (h.x >= 1.0f) ? 0.0f : h.x;
        v.y = (h.y >= 1.0f) ? 0.0f : h.y;
        v.z = (h.z >= 1.0f) ? 0.0f : h.z;
        v.w = (h.w >= 1.0f) ? 0.0f : h.w;
    }
}

extern "C" void kernel_launch(void* const* d_in, const int* in_sizes, int n_in,
                              void* d_out, int out_size, void* d_ws, size_t ws_size,
                              hipStream_t stream) {
    const float* x = (const float*)d_in[0];
    float* out = (float*)d_out;

    const int total = in_sizes[0];        // 33,554,432
    const int N = total / 4;              // per-timestep elements: 8,388,608
    const int n4 = N / 4;                 // float4 slots per timestep: 2,097,152

    const int block = 256;
    const int grid = (n4 + block - 1) / block;  // 8192 exact

    lif_spike_kernel<<<grid, block, 0, stream>>>(
        (const f32x4*)x, (f32x4*)out, n4);
}